// Round 8
// baseline (13278.191 us; speedup 1.0000x reference)
//
#include <hip/hip_runtime.h>

#define NLAYER 6
#define NB     128     // batch
#define NT     512     // seq len
#define DIN    128     // layer-0 input size
#define NH     256     // hidden
#define NBLK   48      // 6 layers x 8 batch-groups: ONE block per (l,bg)
// Tagged x-ring: each value is one 4B word = (bf16<<16)|step_tag.
// Slot = [128 batch rows][256 words] = [128][128 u64].
#define TSLOT_U64 (NB*NH/2)

typedef __attribute__((ext_vector_type(8))) short short8;
typedef __attribute__((ext_vector_type(4))) float f32x4;
typedef unsigned long long u64;

__device__ __forceinline__ unsigned f2bf2(float lo, float hi){
  unsigned a = __float_as_uint(lo), b = __float_as_uint(hi);
  a = (a + 0x7fffu + ((a>>16)&1u)) >> 16;   // RNE bf16
  b = (b + 0x7fffu + ((b>>16)&1u)) >> 16;
  return a | (b<<16);
}
__device__ __forceinline__ u64 f2bf4(float a, float b, float c, float d){
  return (u64)f2bf2(a,b) | ((u64)f2bf2(c,d) << 32);
}
__device__ __forceinline__ short8 pack16(u64 lo, u64 hi){
  union { u64 u[2]; short8 v; } w; w.u[0]=lo; w.u[1]=hi; return w.v;
}
// 8 consecutive fp32 -> one MFMA bf16 fragment (4 VGPRs)
__device__ __forceinline__ short8 ld8f_frag(const float* p){
  f32x4 a = *(const f32x4*)p;
  f32x4 b = *(const f32x4*)(p+4);
  return pack16(f2bf4(a[0],a[1],a[2],a[3]), f2bf4(b[0],b[1],b[2],b[3]));
}

__device__ __forceinline__ float sigmf(float v){ return 1.0f/(1.0f + __expf(-v)); }
__device__ __forceinline__ float tanhfast(float v){
  v = fminf(fmaxf(v, -15.0f), 15.0f);
  float e = __expf(2.0f*v);
  return (e - 1.0f)/(e + 1.0f);
}

// Agent-scope relaxed atomics (fabric-coherent) — the r3-proven protocol.
// Tagged words self-validate, so no ordering, no drains, no tag arrays.
__device__ __forceinline__ int ld_flag(const int* p){
  return __hip_atomic_load(p, __ATOMIC_RELAXED, __HIP_MEMORY_SCOPE_AGENT);
}
__device__ __forceinline__ void st_flag(int* p, int v){
  __hip_atomic_store(p, v, __ATOMIC_RELAXED, __HIP_MEMORY_SCOPE_AGENT);
}
__device__ __forceinline__ u64 ring_ld(const u64* p){
  return __hip_atomic_load(p, __ATOMIC_RELAXED, __HIP_MEMORY_SCOPE_AGENT);
}
__device__ __forceinline__ void ring_st(u64* p, u64 v){
  __hip_atomic_store(p, v, __ATOMIC_RELAXED, __HIP_MEMORY_SCOPE_AGENT);
}

// one h value + step tag -> self-validating 4B word
__device__ __forceinline__ unsigned tagw(float f, unsigned tag){
  unsigned a = __float_as_uint(f);
  return ((a + 0x7fffu + ((a>>16)&1u)) & 0xffff0000u) | tag;   // RNE bf16 hi16
}
// strip tags: one tagged u64 (2 words) -> one packed u32 (2 bf16)
__device__ __forceinline__ unsigned strip2(u64 q){
  return __builtin_amdgcn_perm((unsigned)(q>>32), (unsigned)q, 0x07060302u);
}
// tag-mismatch mask for two tagged u64 (4 words)
__device__ __forceinline__ unsigned tchk(u64 q0, u64 q1, u64 tag64){
  u64 m = (q0 ^ tag64) | (q1 ^ tag64);
  return (unsigned)(m | (m >> 32)) & 0xffffu;
}

// MFMA B-fragment from an LDS plane (row pitch 132 u32 = 528B, r3-verified).
__device__ __forceinline__ short8 lds_frag(const unsigned* __restrict__ buf, int row, int soff){
  return *(const short8*)((const short*)buf + row*264 + soff);
}

// ONE 1024-thread block per (layer, batch-group): the entire h-recurrence is
// intra-CU (LDS + barrier, zero fabric ops on the critical path). Wave s owns
// output slice s (16 cols x 16 batch rows). Only the x-edge (prev layer's h)
// crosses blocks, via the r3 tagged ring, prefetched a step ahead so its
// latency hides under the MFMAs.
template<int NKX>
__device__ __forceinline__ void lstm_run(
    const float* __restrict__ x,  const float* __restrict__ h0,
    const float* __restrict__ c0, const float* __restrict__ wx,
    const float* __restrict__ wh, const float* __restrict__ bi,
    const float* __restrict__ bh, float* __restrict__ out,
    int* __restrict__ acks, u64* __restrict__ ring, unsigned (*ldsb)[2112],
    int Wv, int l, int bg)
{
  constexpr int KIT  = NKX + 8;      // total k-iterations (12 or 16)
  constexpr int KX   = NKX*32;       // input width (128 or 256)
  constexpr bool HASX = (NKX == 8);  // x comes from the prev-layer ring
  const int tid  = threadIdx.x;
  const int lane = tid & 63;
  const int s    = tid >> 6;         // wave = slice 0..15
  const int l15  = lane & 15;
  const int quad = lane >> 4;
  const int bloc = bg*16 + l15;      // this lane's batch row
  const int jcol = s*16 + quad*4;    // this lane's first hidden col
  const int Wm   = Wv - 1;

  // ---- A fragments: stationary (4 gates x KIT kts x 4 VGPR) ----
  short8 A[4][KIT];
  #pragma unroll
  for (int q = 0; q < 4; ++q){
    const float* wrow_x = wx + (size_t)(q*NH + s*16 + l15)*KX;
    const float* wrow_h = wh + (size_t)(q*NH + s*16 + l15)*NH;
    #pragma unroll
    for (int kt = 0; kt < KIT; ++kt){
      int k0 = kt*32 + quad*8;
      A[q][kt] = (k0 < KX) ? ld8f_frag(wrow_x + k0)
                           : ld8f_frag(wrow_h + (k0 - KX));
    }
  }

  f32x4 bsv[4];
  #pragma unroll
  for (int q = 0; q < 4; ++q){
    f32x4 a = *(const f32x4*)(bi + q*NH + jcol);
    f32x4 b = *(const f32x4*)(bh + q*NH + jcol);
    bsv[q] = a + b;
  }
  float cc[4];
  {
    f32x4 cv = *(const f32x4*)(c0 + ((size_t)l*NB + bloc)*NH + jcol);
    cc[0]=cv[0]; cc[1]=cv[1]; cc[2]=cv[2]; cc[3]=cv[3];
  }

  const u64* ringP = HASX ? ring + (size_t)(l-1)*Wv*TSLOT_U64 : nullptr;
  u64*       ringOwn = ring + (size_t)l*Wv*TSLOT_U64;
  const bool pub = (l < NLAYER-1);          // layer 5's h feeds nothing
  const int* ackOwn  = acks + l*8 + bg;     // consumer(l+1)'s watermark
  int*       ackPrev = HASX ? acks + (l-1)*8 + bg : nullptr;
  int ackmin = 0;

  unsigned* ldsX0 = ldsb[0]; unsigned* ldsX1 = ldsb[1];
  unsigned* ldsH0 = ldsb[2]; unsigned* ldsH1 = ldsb[3];

  // ---- prologue staging: h0 and x_0 into LDS ----
  {
    // h0: wave s stages batch row s (all 1024 threads, 4 floats/lane)
    const float* ph = h0 + ((size_t)l*NB + bg*16 + s)*NH + lane*4;
    f32x4 v = *(const f32x4*)ph;
    *(u64*)(ldsH0 + s*132 + lane*2) = f2bf4(v[0],v[1],v[2],v[3]);
  }
  if constexpr (HASX){
    // x_0 = prev layer's h_0: tagged spin on ring slot 0 (tag 1)
    const u64* bx0 = ringP + (size_t)(bg*16 + s)*128 + lane*2;
    u64 q0, q1; int guard = 0;
    for (;;){
      q0 = ring_ld(bx0); q1 = ring_ld(bx0 + 1);
      if (__ballot(tchk(q0, q1, 0x0000000100000001ull) == 0u) == ~0ull) break;
      __builtin_amdgcn_s_sleep(1);
      if (++guard > (1<<22)) break;   // failsafe only
    }
    *(u64*)(ldsX0 + s*132 + lane*2) = (u64)strip2(q0) | ((u64)strip2(q1) << 32);
  } else {
    if (tid < 512){
      const int r = tid >> 5, c = tid & 31;
      f32x4 v = *(const f32x4*)(x + ((size_t)(bg*16 + r)*NT + 0)*DIN + c*4);
      *(u64*)(ldsX0 + r*132 + c*2) = f2bf4(v[0],v[1],v[2],v[3]);
    }
  }
  __syncthreads();

  for (int t = 0; t < NT; ++t){
    // WAR guard (producers only): consumer must have passed slot t-Wv.
    // Acks jump by 8 -> cached watermark, fabric poll ~never in steady state.
    if (pub && t >= Wv){
      const int need = t - Wv + 1;
      if (ackmin < need){
        int v, guard = 0;
        for (;;){
          v = ld_flag(ackOwn);
          if (v >= need) break;
          __builtin_amdgcn_s_sleep(1);
          if (++guard > (1<<22)) break;
        }
        ackmin = v;
      }
    }

    unsigned* ldsXc = (t & 1) ? ldsX1 : ldsX0;
    unsigned* ldsXn = (t & 1) ? ldsX0 : ldsX1;
    unsigned* ldsHc = (t & 1) ? ldsH1 : ldsH0;
    unsigned* ldsHn = (t & 1) ? ldsH0 : ldsH1;

    // ---- issue x_{t+1} prefetch (latency hides under the MFMAs) ----
    const bool pf = (t + 1 < NT);
    u64 q0 = 0, q1 = 0; f32x4 pv;
    const u64* bxp = nullptr;
    if constexpr (HASX){
      if (pf){
        bxp = ringP + (size_t)((t+1)&Wm)*TSLOT_U64 + (size_t)(bg*16 + s)*128 + lane*2;
        q0 = ring_ld(bxp); q1 = ring_ld(bxp + 1);
      }
    } else {
      if (pf && tid < 512)
        pv = *(const f32x4*)(x + ((size_t)(bg*16 + (tid>>5))*NT + (t+1))*DIN + (tid&31)*4);
    }

    // ---- B fragments from LDS (h_{t-1} already here: barrier last step) ----
    short8 Bx[NKX], Bh[8];
    #pragma unroll
    for (int k = 0; k < NKX; ++k) Bx[k] = lds_frag(ldsXc, l15, quad*8 + k*32);
    #pragma unroll
    for (int k = 0; k < 8; ++k)   Bh[k] = lds_frag(ldsHc, l15, quad*8 + k*32);

    // ---- MFMAs: x-part then h-part ----
    f32x4 a0 = {0,0,0,0}, a1 = {0,0,0,0}, a2 = {0,0,0,0}, a3 = {0,0,0,0};
    #pragma unroll
    for (int k = 0; k < NKX; ++k){
      a0 = __builtin_amdgcn_mfma_f32_16x16x32_bf16(A[0][k], Bx[k], a0, 0, 0, 0);
      a1 = __builtin_amdgcn_mfma_f32_16x16x32_bf16(A[1][k], Bx[k], a1, 0, 0, 0);
      a2 = __builtin_amdgcn_mfma_f32_16x16x32_bf16(A[2][k], Bx[k], a2, 0, 0, 0);
      a3 = __builtin_amdgcn_mfma_f32_16x16x32_bf16(A[3][k], Bx[k], a3, 0, 0, 0);
    }
    #pragma unroll
    for (int k = 0; k < 8; ++k){
      a0 = __builtin_amdgcn_mfma_f32_16x16x32_bf16(A[0][NKX+k], Bh[k], a0, 0, 0, 0);
      a1 = __builtin_amdgcn_mfma_f32_16x16x32_bf16(A[1][NKX+k], Bh[k], a1, 0, 0, 0);
      a2 = __builtin_amdgcn_mfma_f32_16x16x32_bf16(A[2][NKX+k], Bh[k], a2, 0, 0, 0);
      a3 = __builtin_amdgcn_mfma_f32_16x16x32_bf16(A[3][NKX+k], Bh[k], a3, 0, 0, 0);
    }

    // ---- finish x_{t+1} prefetch: validate tags (t+2), write other buffer ----
    if constexpr (HASX){
      if (pf){
        const u64 t64 = (u64)(unsigned)(t+2) * 0x0000000100000001ull;
        int guard = 0;
        for (;;){
          if (__ballot(tchk(q0, q1, t64) == 0u) == ~0ull) break;
          __builtin_amdgcn_s_sleep(1);
          if (++guard > (1<<22)) break;   // failsafe only
          q0 = ring_ld(bxp); q1 = ring_ld(bxp + 1);
        }
        *(u64*)(ldsXn + s*132 + lane*2) = (u64)strip2(q0) | ((u64)strip2(q1) << 32);
      }
    } else {
      if (pf && tid < 512)
        *(u64*)(ldsXn + (tid>>5)*132 + (tid&31)*2) = f2bf4(pv[0],pv[1],pv[2],pv[3]);
    }

    // ---- fused gate nonlinearities + state update ----
    float hv[4];
    #pragma unroll
    for (int r = 0; r < 4; ++r){
      float ig = sigmf(a0[r] + bsv[0][r]);
      float fg = sigmf(a1[r] + bsv[1][r]);
      float gv = tanhfast(a2[r] + bsv[2][r]);
      float og = sigmf(a3[r] + bsv[3][r]);
      float cn = fg*cc[r] + ig*gv;
      cc[r] = cn;
      hv[r] = og * tanhfast(cn);
    }

    // ---- h_t -> LDS (the entire recurrence edge: one store + barrier) ----
    *(u64*)(ldsHn + l15*132 + s*8 + quad*2) = f2bf4(hv[0], hv[1], hv[2], hv[3]);

    // ---- publish h_t for layer l+1 (tagged, fire-and-forget) ----
    if (pub){
      const unsigned otag = (unsigned)(t+1);
      u64* hp = ringOwn + (size_t)(t&Wm)*TSLOT_U64 + (size_t)bloc*128 + s*8 + quad*2;
      ring_st(hp,     (u64)tagw(hv[0], otag) | ((u64)tagw(hv[1], otag) << 32));
      ring_st(hp + 1, (u64)tagw(hv[2], otag) | ((u64)tagw(hv[3], otag) << 32));
    }
    if (t == NT-1){
      f32x4 ov; ov[0]=hv[0]; ov[1]=hv[1]; ov[2]=hv[2]; ov[3]=hv[3];
      *(f32x4*)(out + ((size_t)l*NB + bloc)*NH + jcol) = ov;
    }

    // amortized consumption ack to the previous layer (x_{t+1} validated above)
    if (HASX && ((t & 7) == 7) && tid == 0) st_flag(ackPrev, t+1);

    __syncthreads();   // h_t plane complete; x_{t+1} staged; old buffers free
  }
}

__global__ __launch_bounds__(1024, 1)
void lstm_pipe(const float* __restrict__ x,   const float* __restrict__ h0,
               const float* __restrict__ c0,  const float* __restrict__ wih0,
               const float* __restrict__ wih, const float* __restrict__ whh,
               const float* __restrict__ bih, const float* __restrict__ bhh,
               float* __restrict__ out, int* __restrict__ acks,
               u64* __restrict__ ring, int Wv)
{
  // bid = bg + 8*l: with bid%8 XCD round-robin, all 6 layers of a batch-group
  // share one XCD (x-edge L2 locality; correctness never depends on it).
  __shared__ unsigned ldsb[4][2112];   // [x0,x1,h0,h1][16 rows x 132 u32]
  const int bid = blockIdx.x;
  const int bg  = bid & 7;
  const int l   = bid >> 3;

  if (l == 0)
    lstm_run<4>(x, h0, c0, wih0, whh, bih, bhh,
                out, acks, ring, ldsb, Wv, 0, bg);
  else
    lstm_run<8>(x, h0, c0,
                wih + (size_t)(l-1)*(4*NH*NH),
                whh + (size_t)l*(4*NH*NH),
                bih + (size_t)l*(4*NH),
                bhh + (size_t)l*(4*NH),
                out, acks, ring, ldsb, Wv, l, bg);
}

extern "C" void kernel_launch(void* const* d_in, const int* in_sizes, int n_in,
                              void* d_out, int out_size, void* d_ws, size_t ws_size,
                              hipStream_t stream)
{
  (void)in_sizes; (void)n_in; (void)out_size;
  const float* x    = (const float*)d_in[0];
  const float* h0   = (const float*)d_in[1];
  const float* c0   = (const float*)d_in[2];
  const float* wih0 = (const float*)d_in[3];
  const float* wih  = (const float*)d_in[4];
  const float* whh  = (const float*)d_in[5];
  const float* bih  = (const float*)d_in[6];
  const float* bhh  = (const float*)d_in[7];

  // x-ring depth 32 (25 MB tagged); amortized acks give ~24 steps of slack.
  int Wv = 32;
  size_t ringB;
  for (;;){
    ringB = (size_t)NLAYER*Wv*TSLOT_U64*8;
    if (8192 + ringB <= ws_size || Wv <= 8) break;
    Wv >>= 1;
  }

  int* acks = (int*)d_ws;                    // 48 ints, padded to 8KB
  u64* ring = (u64*)((char*)d_ws + 8192);

  // Ring MUST be cleared every launch: a graph replay would otherwise find
  // the previous run's tags and accept stale data. Tag 0 never validates.
  (void)hipMemsetAsync(d_ws, 0, 8192 + ringB, stream);
  hipLaunchKernelGGL(lstm_pipe, dim3(NBLK), dim3(1024), 0, stream,
                     x, h0, c0, wih0, wih, whh, bih, bhh,
                     (float*)d_out, acks, ring, Wv);
}

// Round 9
// 1923.332 us; speedup vs baseline: 6.9037x; 6.9037x over previous
//
#include <hip/hip_runtime.h>

#define NLAYER 6
#define NB     128     // batch
#define NT     512     // seq len
#define DIN    128     // layer-0 input size
#define NH     256     // hidden
#define NBLK   192     // 6 layers x 8 batch-groups x 4 blocks
// Tagged ring: each h value is one 4B word = (bf16<<16)|step_tag.
// Slot = [128 batch rows][256 words] = 128KB = 16384 u64. Plane (one bg) =
// 16 rows x 1KB = 2048 u64.
#define TSLOT_U64 (NB*NH/2)

typedef __attribute__((ext_vector_type(8))) short short8;
typedef __attribute__((ext_vector_type(4))) float f32x4;
typedef unsigned long long u64;

__device__ __forceinline__ unsigned f2bf2(float lo, float hi){
  unsigned a = __float_as_uint(lo), b = __float_as_uint(hi);
  a = (a + 0x7fffu + ((a>>16)&1u)) >> 16;   // RNE bf16
  b = (b + 0x7fffu + ((b>>16)&1u)) >> 16;
  return a | (b<<16);
}
__device__ __forceinline__ u64 f2bf4(float a, float b, float c, float d){
  return (u64)f2bf2(a,b) | ((u64)f2bf2(c,d) << 32);
}
__device__ __forceinline__ short8 pack16(u64 lo, u64 hi){
  union { u64 u[2]; short8 v; } w; w.u[0]=lo; w.u[1]=hi; return w.v;
}
// 8 consecutive fp32 -> one MFMA bf16 fragment (4 VGPRs)
__device__ __forceinline__ short8 ld8f_frag(const float* p){
  f32x4 a = *(const f32x4*)p;
  f32x4 b = *(const f32x4*)(p+4);
  return pack16(f2bf4(a[0],a[1],a[2],a[3]), f2bf4(b[0],b[1],b[2],b[3]));
}

__device__ __forceinline__ float sigmf(float v){ return 1.0f/(1.0f + __expf(-v)); }
__device__ __forceinline__ float tanhfast(float v){
  v = fminf(fmaxf(v, -15.0f), 15.0f);
  float e = __expf(2.0f*v);
  return (e - 1.0f)/(e + 1.0f);
}

// Relaxed agent-scope atomics (fabric/MALL-coherent). With self-validating
// tagged words the ONLY requirement is per-4B-word atomic visibility: no
// store ordering, no vmcnt drain, no separate tag arrays.
__device__ __forceinline__ int ld_flag(const int* p){
  return __hip_atomic_load(p, __ATOMIC_RELAXED, __HIP_MEMORY_SCOPE_AGENT);
}
__device__ __forceinline__ void st_flag(int* p, int v){
  __hip_atomic_store(p, v, __ATOMIC_RELAXED, __HIP_MEMORY_SCOPE_AGENT);
}
__device__ __forceinline__ u64 ring_ld(const u64* p){
  return __hip_atomic_load(p, __ATOMIC_RELAXED, __HIP_MEMORY_SCOPE_AGENT);
}
__device__ __forceinline__ void ring_st(u64* p, u64 v){
  __hip_atomic_store(p, v, __ATOMIC_RELAXED, __HIP_MEMORY_SCOPE_AGENT);
}

// one h value + step tag -> self-validating 4B word
__device__ __forceinline__ unsigned tagw(float f, unsigned tag){
  unsigned a = __float_as_uint(f);
  return ((a + 0x7fffu + ((a>>16)&1u)) & 0xffff0000u) | tag;   // RNE bf16 in hi16
}
// strip tags: one tagged u64 (2 words) -> one packed u32 (2 bf16)
__device__ __forceinline__ unsigned strip2(u64 q){
  return __builtin_amdgcn_perm((unsigned)(q>>32), (unsigned)q, 0x07060302u);
}

// MFMA B-fragment from a staged LDS plane (row pitch 132 u32 = 528B).
__device__ __forceinline__ short8 lds_frag(const unsigned* __restrict__ buf, int row, int soff){
  return *(const short8*)((const short*)buf + row*264 + soff);
}

// Block = 4 slices x 16 batch rows. Wave wv owns slice s = b*4+wv. h/x are
// staged once per block into LDS via POLLING tagged loads (the stage IS the
// sync); A stationary in regs; publish is fire-and-forget tagged stores.
template<int NKX>
__device__ __forceinline__ void lstm_run(
    const float* __restrict__ x,  const float* __restrict__ h0,
    const float* __restrict__ c0, const float* __restrict__ wx,
    const float* __restrict__ wh, const float* __restrict__ bi,
    const float* __restrict__ bh, float* __restrict__ out,
    int* __restrict__ acks, u64* __restrict__ ring, unsigned (*ldsb)[2112],
    int Wv, int l, int bg, int s, int wv, int lane)
{
  constexpr int KIT  = NKX + 8;      // total k-iterations (12 or 16)
  constexpr int KX   = NKX*32;       // input width (128 or 256)
  constexpr bool HASX = (NKX == 8);  // x comes from the prev-layer ring
  const int l15  = lane & 15;
  const int quad = lane >> 4;
  const int bloc = bg*16 + l15;      // this lane's batch row
  const int jcol = s*16 + quad*4;    // this lane's first hidden col
  const int Wm   = Wv - 1;

  // ---- A fragments: stationary (4 gates x KIT kts x 4 VGPR) ----
  short8 A[4][KIT];
  #pragma unroll
  for (int q = 0; q < 4; ++q){
    const float* wrow_x = wx + (size_t)(q*NH + s*16 + l15)*KX;
    const float* wrow_h = wh + (size_t)(q*NH + s*16 + l15)*NH;
    #pragma unroll
    for (int kt = 0; kt < KIT; ++kt){
      int k0 = kt*32 + quad*8;
      A[q][kt] = (k0 < KX) ? ld8f_frag(wrow_x + k0)
                           : ld8f_frag(wrow_h + (k0 - KX));
    }
  }

  f32x4 bsv[4];
  #pragma unroll
  for (int q = 0; q < 4; ++q){
    f32x4 a = *(const f32x4*)(bi + q*NH + jcol);
    f32x4 b = *(const f32x4*)(bh + q*NH + jcol);
    bsv[q] = a + b;
  }
  float cc[4];
  {
    f32x4 cv = *(const f32x4*)(c0 + ((size_t)l*NB + bloc)*NH + jcol);
    cc[0]=cv[0]; cc[1]=cv[1]; cc[2]=cv[2]; cc[3]=cv[3];
  }

  const int* ackOwn = acks + (l*8 + bg)*16;                     // layer l+1 watermarks
  int* ackPrevW = HASX ? acks + ((l-1)*8 + bg)*16 + s : nullptr;
  const u64* ringPrev = HASX ? ring + (size_t)(l-1)*Wv*TSLOT_U64 : nullptr;
  u64*       ringOwn  = ring + (size_t)l*Wv*TSLOT_U64;
  const bool lastL = (l == NLAYER-1);
  const bool wrap  = (Wv < NT);
  int ackmin = 0;

  // per-lane stage geometry: chunk c covers plane row wv*4+c, 16B per lane
  const int sbase = wv*512 + lane*2;   // u64 index within a 2048-u64 plane

  for (int t = 0; t < NT; ++t){
    const int slot  = t & Wm;
    const int pslot = (t-1) & Wm;

    // WAR guard (wrap only): layer l+1 must have consumed slot t-Wv.
    // Consumers ack every 8 steps; cached watermark -> fabric poll ~1/8 steps.
    if (wrap && !lastL && t >= Wv){
      const int need = t - Wv + 1;
      if (ackmin < need){
        int v = 0, guard = 0;
        for (;;){
          v = (lane < 16) ? ld_flag(ackOwn + lane) : 0x7fffffff;
          if (__ballot(v >= need) == ~0ull) break;
          __builtin_amdgcn_s_sleep(1);
          if (++guard > (1<<22)) break;
        }
        int m = v;
        #pragma unroll
        for (int o = 8; o; o >>= 1) m = min(m, __shfl_xor(m, o));
        ackmin = __shfl(m, 0);
      }
    }

    short8 Bx[NKX];
    if constexpr (!HASX){
      // layer 0: x is a plain cached load, issued before the poll
      const float* px = x + ((size_t)bloc*NT + t)*DIN + quad*8;
      #pragma unroll
      for (int k = 0; k < NKX; ++k) Bx[k] = ld8f_frag(px + k*32);
    }

    // ---- polling stage: tagged coalesced loads, retry until valid.
    // HOT poll (edit 1): sleep only every 8th failed iteration — polls are
    // mostly MALL-hits (r3 FETCH evidence), so spinning hotter cuts detect
    // latency without meaningful fabric pressure.
    const u64* srcX = HASX ? ringPrev + (size_t)slot*TSLOT_U64 + bg*2048 : nullptr;
    const u64* srcH = (t > 0) ? ringOwn + (size_t)pslot*TSLOT_U64 + bg*2048 : nullptr;
    unsigned* ldsX = ldsb[(t&1)*2 + 0];
    unsigned* ldsH = ldsb[(t&1)*2 + 1];
    u64 qx[8], qh[8];
    {
      bool okx = !HASX, okh = (srcH == nullptr);
      const u64 tx2 = (u64)(unsigned)(t+1) * 0x0000000100000001ull;
      const u64 th2 = (u64)(unsigned)t     * 0x0000000100000001ull;
      int guard = 0;
      while (!(okx & okh)){
        if (!okh){
          #pragma unroll
          for (int c = 0; c < 4; ++c){
            qh[c*2]   = ring_ld(srcH + sbase + c*128);
            qh[c*2+1] = ring_ld(srcH + sbase + c*128 + 1);
          }
        }
        if (!okx){
          #pragma unroll
          for (int c = 0; c < 4; ++c){
            qx[c*2]   = ring_ld(srcX + sbase + c*128);
            qx[c*2+1] = ring_ld(srcX + sbase + c*128 + 1);
          }
        }
        if (!okh){
          u64 m = 0;
          #pragma unroll
          for (int i = 0; i < 8; ++i) m |= qh[i] ^ th2;
          okh = (__ballot(((unsigned)(m | (m>>32)) & 0xffffu) == 0u) == ~0ull);
        }
        if (!okx){
          u64 m = 0;
          #pragma unroll
          for (int i = 0; i < 8; ++i) m |= qx[i] ^ tx2;
          okx = (__ballot(((unsigned)(m | (m>>32)) & 0xffffu) == 0u) == ~0ull);
        }
        if (okx & okh) break;
        if ((++guard & 7) == 7) __builtin_amdgcn_s_sleep(1);
        if (guard > (1<<22)) break;   // failsafe only
      }
    }
    // strip tags -> packed bf16 planes in LDS (lane-contiguous: conflict-free)
    if constexpr (HASX){
      #pragma unroll
      for (int c = 0; c < 4; ++c)
        *(u64*)(ldsX + (wv*4+c)*132 + lane*2) =
            (u64)strip2(qx[c*2]) | ((u64)strip2(qx[c*2+1]) << 32);
    }
    if (srcH){
      #pragma unroll
      for (int c = 0; c < 4; ++c)
        *(u64*)(ldsH + (wv*4+c)*132 + lane*2) =
            (u64)strip2(qh[c*2]) | ((u64)strip2(qh[c*2+1]) << 32);
    }
    __syncthreads();

    // ack prev-layer consumption every 8 steps (values were tag-checked ->
    // loads complete; relaxed agent flag is sufficient for the WAR watermark)
    if (HASX && wrap && ((t & 7) == 7) && lane == 0) st_flag(ackPrevW, t+1);

    if constexpr (HASX){
      #pragma unroll
      for (int k = 0; k < NKX; ++k) Bx[k] = lds_frag(ldsX, l15, quad*8 + k*32);
    }
    short8 Bh[8];
    if (t == 0){
      const float* ph = h0 + ((size_t)l*NB + bloc)*NH + quad*8;
      #pragma unroll
      for (int k = 0; k < 8; ++k) Bh[k] = ld8f_frag(ph + k*32);
    } else {
      #pragma unroll
      for (int k = 0; k < 8; ++k) Bh[k] = lds_frag(ldsH, l15, quad*8 + k*32);
    }

    // ---- MFMAs: x-part then h-part ----
    f32x4 a0 = {0,0,0,0}, a1 = {0,0,0,0}, a2 = {0,0,0,0}, a3 = {0,0,0,0};
    #pragma unroll
    for (int k = 0; k < NKX; ++k){
      a0 = __builtin_amdgcn_mfma_f32_16x16x32_bf16(A[0][k], Bx[k], a0, 0, 0, 0);
      a1 = __builtin_amdgcn_mfma_f32_16x16x32_bf16(A[1][k], Bx[k], a1, 0, 0, 0);
      a2 = __builtin_amdgcn_mfma_f32_16x16x32_bf16(A[2][k], Bx[k], a2, 0, 0, 0);
      a3 = __builtin_amdgcn_mfma_f32_16x16x32_bf16(A[3][k], Bx[k], a3, 0, 0, 0);
    }
    #pragma unroll
    for (int k = 0; k < 8; ++k){
      a0 = __builtin_amdgcn_mfma_f32_16x16x32_bf16(A[0][NKX+k], Bh[k], a0, 0, 0, 0);
      a1 = __builtin_amdgcn_mfma_f32_16x16x32_bf16(A[1][NKX+k], Bh[k], a1, 0, 0, 0);
      a2 = __builtin_amdgcn_mfma_f32_16x16x32_bf16(A[2][NKX+k], Bh[k], a2, 0, 0, 0);
      a3 = __builtin_amdgcn_mfma_f32_16x16x32_bf16(A[3][NKX+k], Bh[k], a3, 0, 0, 0);
    }

    // ---- gates + state update, publishing each 8B as soon as ready ----
    // (edit 2: the first tagged store issues ~60-80cy earlier, shortening
    //  the publish->detect chain seen by all 16 downstream waves)
    u64* hp = ringOwn + (size_t)slot*TSLOT_U64 + (size_t)bloc*128 + s*8 + quad*2;
    const unsigned otag = (unsigned)(t+1);
    float hv[4];
    #pragma unroll
    for (int r = 0; r < 2; ++r){
      float ig = sigmf(a0[r] + bsv[0][r]);
      float fg = sigmf(a1[r] + bsv[1][r]);
      float gv = tanhfast(a2[r] + bsv[2][r]);
      float og = sigmf(a3[r] + bsv[3][r]);
      float cn = fg*cc[r] + ig*gv;
      cc[r] = cn;
      hv[r] = og * tanhfast(cn);
    }
    ring_st(hp, (u64)tagw(hv[0], otag) | ((u64)tagw(hv[1], otag) << 32));
    #pragma unroll
    for (int r = 2; r < 4; ++r){
      float ig = sigmf(a0[r] + bsv[0][r]);
      float fg = sigmf(a1[r] + bsv[1][r]);
      float gv = tanhfast(a2[r] + bsv[2][r]);
      float og = sigmf(a3[r] + bsv[3][r]);
      float cn = fg*cc[r] + ig*gv;
      cc[r] = cn;
      hv[r] = og * tanhfast(cn);
    }
    ring_st(hp + 1, (u64)tagw(hv[2], otag) | ((u64)tagw(hv[3], otag) << 32));

    if (t == NT-1){
      f32x4 ov; ov[0]=hv[0]; ov[1]=hv[1]; ov[2]=hv[2]; ov[3]=hv[3];
      *(f32x4*)(out + ((size_t)l*NB + bloc)*NH + jcol) = ov;
    }
  }
}

__global__ __launch_bounds__(256, 1)
void lstm_pipe(const float* __restrict__ x,   const float* __restrict__ h0,
               const float* __restrict__ c0,  const float* __restrict__ wih0,
               const float* __restrict__ wih, const float* __restrict__ whh,
               const float* __restrict__ bih, const float* __restrict__ bhh,
               float* __restrict__ out, int* __restrict__ acks,
               u64* __restrict__ ring, int Wv)
{
  // XCD clustering: bid = bg + 8*(l*4 + b). With bid%8 XCD round-robin, the
  // entire 6-layer pipeline of batch-group bg (24 blocks) lands on one XCD.
  __shared__ unsigned ldsb[4][2112];   // [buf 2][plane x/h][16 rows x 132 u32]
  const int bid  = blockIdx.x;
  const int bg   = bid & 7;
  const int j    = bid >> 3;
  const int l    = j >> 2;
  const int b    = j & 3;
  const int lane = threadIdx.x & 63;
  const int wv   = threadIdx.x >> 6;
  const int s    = b*4 + wv;          // this wave's slice (0..15)

  if (l == 0)
    lstm_run<4>(x, h0, c0, wih0, whh, bih, bhh,
                out, acks, ring, ldsb, Wv, 0, bg, s, wv, lane);
  else
    lstm_run<8>(x, h0, c0,
                wih + (size_t)(l-1)*(4*NH*NH),
                whh + (size_t)l*(4*NH*NH),
                bih + (size_t)l*(4*NH),
                bhh + (size_t)l*(4*NH),
                out, acks, ring, ldsb, Wv, l, bg, s, wv, lane);
}

extern "C" void kernel_launch(void* const* d_in, const int* in_sizes, int n_in,
                              void* d_out, int out_size, void* d_ws, size_t ws_size,
                              hipStream_t stream)
{
  (void)in_sizes; (void)n_in; (void)out_size;
  const float* x    = (const float*)d_in[0];
  const float* h0   = (const float*)d_in[1];
  const float* c0   = (const float*)d_in[2];
  const float* wih0 = (const float*)d_in[3];
  const float* wih  = (const float*)d_in[4];
  const float* whh  = (const float*)d_in[5];
  const float* bih  = (const float*)d_in[6];
  const float* bhh  = (const float*)d_in[7];

  // Ring depth 32 (25 MB tagged). Own-h cohort is lockstep (skew <= 1) so
  // any depth >= 2 is safe there; cross-layer wrap uses amortized acks.
  int Wv = 32;
  size_t ringB;
  for (;;){
    ringB = (size_t)NLAYER*Wv*TSLOT_U64*8;
    if (8192 + ringB <= ws_size || Wv <= 8) break;
    Wv >>= 1;
  }

  int* acks = (int*)d_ws;                    // 768 ints, padded to 8KB
  u64* ring = (u64*)((char*)d_ws + 8192);

  // Ring MUST be cleared every launch: graph replay would otherwise find the
  // previous run's tags (identical t+1 pattern) and accept stale data.
  // Tag 0 never validates (expected tags are >= 1).
  (void)hipMemsetAsync(d_ws, 0, 8192 + ringB, stream);
  hipLaunchKernelGGL(lstm_pipe, dim3(NBLK), dim3(256), 0, stream,
                     x, h0, c0, wih0, wih, whh, bih, bhh,
                     (float*)d_out, acks, ring, Wv);
}